// Round 18
// baseline (250.250 us; speedup 1.0000x reference)
//
#include <hip/hip_runtime.h>

#define NSIG  65536
#define KAT   512
#define CDIM  64

typedef float f32x4 __attribute__((ext_vector_type(4)));

__device__ __forceinline__ f32x4 splat4(float x) { return (f32x4){x, x, x, x}; }
__device__ __forceinline__ float bcastf(float v, int l) {
  return __int_as_float(__builtin_amdgcn_readlane(__float_as_int(v), l));
}
__device__ __forceinline__ int bcasti(int v, int l) {
  return __builtin_amdgcn_readlane(v, l);
}
__device__ __forceinline__ unsigned umaxu(unsigned a, unsigned b) {
  return a > b ? a : b;
}
__device__ __forceinline__ unsigned dppmax(unsigned v, const int ctrl) {
  switch (ctrl) {
    case 0xB1:  return umaxu(v, (unsigned)__builtin_amdgcn_mov_dpp((int)v, 0xB1, 0xF, 0xF, true));
    case 0x4E:  return umaxu(v, (unsigned)__builtin_amdgcn_mov_dpp((int)v, 0x4E, 0xF, 0xF, true));
    case 0x124: return umaxu(v, (unsigned)__builtin_amdgcn_mov_dpp((int)v, 0x124, 0xF, 0xF, true));
    case 0x128: return umaxu(v, (unsigned)__builtin_amdgcn_mov_dpp((int)v, 0x128, 0xF, 0xF, true));
    default:    return umaxu(v, (unsigned)__builtin_amdgcn_mov_dpp((int)v, 0x142, 0xF, 0xF, true));
  }
}

// G = D^T D  [512][512]; DT[k][c] = D[c][k]
__global__ void k_gram(const float* __restrict__ D, float* __restrict__ G,
                       float* __restrict__ DT) {
  int tid = blockIdx.x * 256 + threadIdx.x;      // 262144 total
  int i = tid >> 9, j = tid & 511;
  float acc = 0.f;
  #pragma unroll 8
  for (int c = 0; c < CDIM; ++c) acc = fmaf(D[c * KAT + i], D[c * KAT + j], acc);
  G[tid] = acc;
  if (tid < KAT * CDIM) {
    int k = tid >> 6, c = tid & 63;
    DT[tid] = D[c * KAT + k];
  }
}

// ST[n][b] = z_e[b][n%64][n/2048][(n/64)%32]   (signal-major staging)
__global__ void k_tr(const float* __restrict__ ze, float* __restrict__ st) {
  __shared__ float tile[64][33];
  int cz = blockIdx.x >> 5;
  int h  = blockIdx.x & 31;
  int t  = threadIdx.x;
  #pragma unroll
  for (int q = 0; q < 8; ++q) {
    int idx = q * 256 + t;
    int b = idx >> 5, w = idx & 31;
    tile[b][w] = ze[b * 65536 + cz * 1024 + h * 32 + w];
  }
  __syncthreads();
  #pragma unroll
  for (int q = 0; q < 8; ++q) {
    int idx = q * 256 + t;
    int w = idx >> 6, b = idx & 63;
    st[(h * 2048 + w * 64 + cz) * 64 + b] = tile[b][w];
  }
}

#define SEL16(e, v0, v1, v2, v3, idx)                                   \
  e = v0[0];                                                            \
  e = ((idx) == 1) ? v0[1] : e;  e = ((idx) == 2) ? v0[2] : e;          \
  e = ((idx) == 3) ? v0[3] : e;  e = ((idx) == 4) ? v1[0] : e;          \
  e = ((idx) == 5) ? v1[1] : e;  e = ((idx) == 6) ? v1[2] : e;          \
  e = ((idx) == 7) ? v1[3] : e;  e = ((idx) == 8) ? v2[0] : e;          \
  e = ((idx) == 9) ? v2[1] : e;  e = ((idx) == 10) ? v2[2] : e;         \
  e = ((idx) == 11) ? v2[3] : e; e = ((idx) == 12) ? v3[0] : e;         \
  e = ((idx) == 13) ? v3[1] : e; e = ((idx) == 14) ? v3[2] : e;         \
  e = ((idx) == 15) ? v3[3] : e;

// SPLIT-WAVE OMP: lanes 0-31 run signal P, lanes 32-63 run signal Q.
// Each lane holds 16 atoms: atom a = (lane&31)*16 + j. One instruction
// stream advances BOTH signals (argmax, scalar chain, ortho all shared).
// cr in 4 f32x4 refs; Q cols 0-2 in LDS (per half), col 3 in registers.
__device__ __forceinline__ void omp_pair(
    f32x4& c0, f32x4& c1, f32x4& c2, f32x4& c3,
    float* __restrict__ QW,            // [2][3][512] floats (12 KB)
    const float* __restrict__ G, const float* __restrict__ DT,
    float* __restrict__ coeffs,
    int nP, int nQ, int lane, float svP, float svQ,
    float& dP_out, float& dQ_out) {
  const int hl = lane & 31;
  const bool loHalf = lane < 32;
  const int sb4 = loHalf ? 0 : 384;    // f32x4 base of this half's Q slice
  unsigned omega = 0xFFFFu;
  int IA0=0, IA1=0, IA2=0, IA3=0, IA4=0;
  int IB0=0, IB1=0, IB2=0, IB3=0, IB4=0;
  float L10=0, L20=0, L21=0, L30=0, L31=0, L32=0;
  float L40=0, L41=0, L42=0, L43=0;
  float d1v=1.f, d2v=1.f, d3v=1.f, d4v=1.f;
  float y0v=0, y1v=0, y2v=0, y3v=0, y4v=0;
  f32x4 Qd0={0,0,0,0}, Qd1={0,0,0,0}, Qd2={0,0,0,0}, Qd3={0,0,0,0};

  f32x4* QW4 = reinterpret_cast<f32x4*>(QW);

  #pragma unroll
  for (int it = 0; it < 5; ++it) {
    // ---- masked |cr| keys (16/lane); per-half DPP argmax ----
    unsigned ab0  = (omega & 1u)          ? (__float_as_uint(c0[0]) & 0x7FFFFFFFu) : 0u;
    unsigned ab1  = ((omega >> 1) & 1u)   ? (__float_as_uint(c0[1]) & 0x7FFFFFFFu) : 0u;
    unsigned ab2  = ((omega >> 2) & 1u)   ? (__float_as_uint(c0[2]) & 0x7FFFFFFFu) : 0u;
    unsigned ab3  = ((omega >> 3) & 1u)   ? (__float_as_uint(c0[3]) & 0x7FFFFFFFu) : 0u;
    unsigned ab4  = ((omega >> 4) & 1u)   ? (__float_as_uint(c1[0]) & 0x7FFFFFFFu) : 0u;
    unsigned ab5  = ((omega >> 5) & 1u)   ? (__float_as_uint(c1[1]) & 0x7FFFFFFFu) : 0u;
    unsigned ab6  = ((omega >> 6) & 1u)   ? (__float_as_uint(c1[2]) & 0x7FFFFFFFu) : 0u;
    unsigned ab7  = ((omega >> 7) & 1u)   ? (__float_as_uint(c1[3]) & 0x7FFFFFFFu) : 0u;
    unsigned ab8  = ((omega >> 8) & 1u)   ? (__float_as_uint(c2[0]) & 0x7FFFFFFFu) : 0u;
    unsigned ab9  = ((omega >> 9) & 1u)   ? (__float_as_uint(c2[1]) & 0x7FFFFFFFu) : 0u;
    unsigned ab10 = ((omega >> 10) & 1u)  ? (__float_as_uint(c2[2]) & 0x7FFFFFFFu) : 0u;
    unsigned ab11 = ((omega >> 11) & 1u)  ? (__float_as_uint(c2[3]) & 0x7FFFFFFFu) : 0u;
    unsigned ab12 = ((omega >> 12) & 1u)  ? (__float_as_uint(c3[0]) & 0x7FFFFFFFu) : 0u;
    unsigned ab13 = ((omega >> 13) & 1u)  ? (__float_as_uint(c3[1]) & 0x7FFFFFFFu) : 0u;
    unsigned ab14 = ((omega >> 14) & 1u)  ? (__float_as_uint(c3[2]) & 0x7FFFFFFFu) : 0u;
    unsigned ab15 = ((omega >> 15) & 1u)  ? (__float_as_uint(c3[3]) & 0x7FFFFFFFu) : 0u;
    unsigned la = umaxu(
        umaxu(umaxu(umaxu(ab0, ab1), umaxu(ab2, ab3)),
              umaxu(umaxu(ab4, ab5), umaxu(ab6, ab7))),
        umaxu(umaxu(umaxu(ab8, ab9), umaxu(ab10, ab11)),
              umaxu(umaxu(ab12, ab13), umaxu(ab14, ab15))));
    unsigned rmax = la;
    rmax = dppmax(rmax, 0xB1);    // quad xor1
    rmax = dppmax(rmax, 0x4E);    // quad xor2
    rmax = dppmax(rmax, 0x124);   // row_ror:4
    rmax = dppmax(rmax, 0x128);   // row_ror:8  -> per-16-row max
    rmax = dppmax(rmax, 0x142);   // row_bcast15 -> lane31/63 = half max
    unsigned gA = (unsigned)bcasti((int)rmax, 31);
    unsigned gB = (unsigned)bcasti((int)rmax, 63);
    unsigned gmu = loHalf ? gA : gB;
    unsigned long long ball = __ballot(la == gmu);
    const int slA = __ffsll((long long)(ball & 0xFFFFFFFFull)) - 1;
    const int slB = 32 + __ffsll((long long)(ball >> 32)) - 1;
    int jb = 15;
    jb = (ab14 == gmu) ? 14 : jb;
    jb = (ab13 == gmu) ? 13 : jb;
    jb = (ab12 == gmu) ? 12 : jb;
    jb = (ab11 == gmu) ? 11 : jb;
    jb = (ab10 == gmu) ? 10 : jb;
    jb = (ab9  == gmu) ? 9  : jb;
    jb = (ab8  == gmu) ? 8  : jb;
    jb = (ab7  == gmu) ? 7  : jb;
    jb = (ab6  == gmu) ? 6  : jb;
    jb = (ab5  == gmu) ? 5  : jb;
    jb = (ab4  == gmu) ? 4  : jb;
    jb = (ab3  == gmu) ? 3  : jb;
    jb = (ab2  == gmu) ? 2  : jb;
    jb = (ab1  == gmu) ? 1  : jb;
    jb = (ab0  == gmu) ? 0  : jb;
    const int jjA = bcasti(jb, slA) & 15;
    const int jjB = bcasti(jb, slB) & 15;
    const int khatA = ((slA & 31) << 4) | jjA;
    const int khatB = ((slB & 31) << 4) | jjB;
    if (lane == slA || lane == slB) omega &= ~(1u << (jb & 15));

    // ---- per-half LDS extracts of w_u = Q_u[khat] (uniform per half) ----
    const int eoffA = ((khatA & 15) >> 2) * 128 + (khatA >> 4) * 4 + (khatA & 3);
    const int eoffB = ((khatB & 15) >> 2) * 128 + (khatB >> 4) * 4 + (khatB & 3);
    const int hbase = loHalf ? eoffA : (1536 + eoffB);
    float w0 = 0.f, w1 = 0.f, w2 = 0.f, w3 = 0.f;
    if (it > 0) w0 = QW[hbase];
    if (it > 1) w1 = QW[hbase + 512];
    if (it > 2) w2 = QW[hbase + 1024];
    if (it > 3) {
      float e; SEL16(e, Qd0, Qd1, Qd2, Qd3, jb)
      float eA = bcastf(e, slA), eB = bcastf(e, slB);
      w3 = loHalf ? eA : eB;
    }

    // ---- new G row (this half's khat); issued before crv extract ----
    const int khat_l = loHalf ? khatA : khatB;
    const float* Gp = G + khat_l * KAT + hl * 16;
    f32x4 na = {0,0,0,0}, nb = {0,0,0,0}, nc = {0,0,0,0}, nd = {0,0,0,0};
    if (it < 4) {
      na = *reinterpret_cast<const f32x4*>(Gp);
      nb = *reinterpret_cast<const f32x4*>(Gp + 4);
      nc = *reinterpret_cast<const f32x4*>(Gp + 8);
      nd = *reinterpret_cast<const f32x4*>(Gp + 12);
    }

    // ---- crv = cr[khat] per half ----
    float crv;
    {
      float e; SEL16(e, c0, c1, c2, c3, jb)
      float eA = bcastf(e, slA), eB = bcastf(e, slB);
      crv = loHalf ? eA : eB;
    }

    // ---- shared scalar chain (serves both halves at once) ----
    float s2v = 1.f - w0 * w0 - w1 * w1 - w2 * w2 - w3 * w3;
    float dn = __builtin_amdgcn_rsqf(s2v);         // rsq(1.0)==1.0 at it==0
    float yn = crv * dn;
    if (it == 0) { IA0 = khatA; IB0 = khatB; y0v = yn; }
    if (it == 1) { IA1 = khatA; IB1 = khatB; y1v = yn; L10 = w0; d1v = dn; }
    if (it == 2) { IA2 = khatA; IB2 = khatB; y2v = yn; L20 = w0; L21 = w1; d2v = dn; }
    if (it == 3) { IA3 = khatA; IB3 = khatB; y3v = yn; L30 = w0; L31 = w1; L32 = w2; d3v = dn; }
    if (it == 4) { IA4 = khatA; IB4 = khatB; y4v = yn; L40 = w0; L41 = w1; L42 = w2; L43 = w3; d4v = dn; }

    // ---- orthogonalize new column; rank-1 update (both halves) ----
    if (it < 4) {
      f32x4 qn0 = na, qn1 = nb, qn2 = nc, qn3 = nd;
      if (it > 0) {
        f32x4 w4 = splat4(-w0);
        qn0 = __builtin_elementwise_fma(w4, QW4[sb4 + 0 * 32 + hl], qn0);
        qn1 = __builtin_elementwise_fma(w4, QW4[sb4 + 1 * 32 + hl], qn1);
        qn2 = __builtin_elementwise_fma(w4, QW4[sb4 + 2 * 32 + hl], qn2);
        qn3 = __builtin_elementwise_fma(w4, QW4[sb4 + 3 * 32 + hl], qn3);
      }
      if (it > 1) {
        f32x4 w4 = splat4(-w1);
        qn0 = __builtin_elementwise_fma(w4, QW4[sb4 + 128 + 0 * 32 + hl], qn0);
        qn1 = __builtin_elementwise_fma(w4, QW4[sb4 + 128 + 1 * 32 + hl], qn1);
        qn2 = __builtin_elementwise_fma(w4, QW4[sb4 + 128 + 2 * 32 + hl], qn2);
        qn3 = __builtin_elementwise_fma(w4, QW4[sb4 + 128 + 3 * 32 + hl], qn3);
      }
      if (it > 2) {
        f32x4 w4 = splat4(-w2);
        qn0 = __builtin_elementwise_fma(w4, QW4[sb4 + 256 + 0 * 32 + hl], qn0);
        qn1 = __builtin_elementwise_fma(w4, QW4[sb4 + 256 + 1 * 32 + hl], qn1);
        qn2 = __builtin_elementwise_fma(w4, QW4[sb4 + 256 + 2 * 32 + hl], qn2);
        qn3 = __builtin_elementwise_fma(w4, QW4[sb4 + 256 + 3 * 32 + hl], qn3);
      }
      f32x4 dn4 = splat4(dn);
      qn0 = qn0 * dn4; qn1 = qn1 * dn4; qn2 = qn2 * dn4; qn3 = qn3 * dn4;
      if (it < 3) {
        QW4[sb4 + it * 128 + 0 * 32 + hl] = qn0;
        QW4[sb4 + it * 128 + 1 * 32 + hl] = qn1;
        QW4[sb4 + it * 128 + 2 * 32 + hl] = qn2;
        QW4[sb4 + it * 128 + 3 * 32 + hl] = qn3;
      } else {
        Qd0 = qn0; Qd1 = qn1; Qd2 = qn2; Qd3 = qn3;
      }
      f32x4 yn4 = splat4(-yn);
      c0 = __builtin_elementwise_fma(yn4, qn0, c0);
      c1 = __builtin_elementwise_fma(yn4, qn1, c1);
      c2 = __builtin_elementwise_fma(yn4, qn2, c2);
      c3 = __builtin_elementwise_fma(yn4, qn3, c3);
    }
  } // it

  // ---- back-substitution (per-lane; each half holds its own values) ----
  float x4 = y4v * d4v;
  float x3 = (y3v - L43 * x4) * d3v;
  float x2 = (y2v - L32 * x3 - L42 * x4) * d2v;
  float x1 = (y1v - L21 * x2 - L31 * x3 - L41 * x4) * d1v;
  float x0 =  y0v - L10 * x1 - L20 * x2 - L30 * x3 - L40 * x4;

  // coeffs: lanes 0-4 write P's entries; lanes 32-36 write Q's
  {
    const int ll = lane & 31;
    if (ll < 5) {
      int ItA = IA0;
      ItA = (ll == 1) ? IA1 : ItA; ItA = (ll == 2) ? IA2 : ItA;
      ItA = (ll == 3) ? IA3 : ItA; ItA = (ll == 4) ? IA4 : ItA;
      int ItB = IB0;
      ItB = (ll == 1) ? IB1 : ItB; ItB = (ll == 2) ? IB2 : ItB;
      ItB = (ll == 3) ? IB3 : ItB; ItB = (ll == 4) ? IB4 : ItB;
      const int It = loHalf ? ItA : ItB;
      float xt = x0;
      xt = (ll == 1) ? x1 : xt; xt = (ll == 2) ? x2 : xt;
      xt = (ll == 3) ? x3 : xt; xt = (ll == 4) ? x4 : xt;
      const int nn = loHalf ? nP : nQ;
      coeffs[(long)It * NSIG + nn] = xt;
    }
  }

  // reconstruction (whole-wave per signal; x_t broadcast from each half)
  const float xA0 = bcastf(x0, 0),  xA1 = bcastf(x1, 0),  xA2 = bcastf(x2, 0);
  const float xA3 = bcastf(x3, 0),  xA4 = bcastf(x4, 0);
  const float xB0 = bcastf(x0, 32), xB1 = bcastf(x1, 32), xB2 = bcastf(x2, 32);
  const float xB3 = bcastf(x3, 32), xB4 = bcastf(x4, 32);
  float recP = xA0 * DT[IA0 * 64 + lane];
  recP = fmaf(xA1, DT[IA1 * 64 + lane], recP);
  recP = fmaf(xA2, DT[IA2 * 64 + lane], recP);
  recP = fmaf(xA3, DT[IA3 * 64 + lane], recP);
  recP = fmaf(xA4, DT[IA4 * 64 + lane], recP);
  float recQ = xB0 * DT[IB0 * 64 + lane];
  recQ = fmaf(xB1, DT[IB1 * 64 + lane], recQ);
  recQ = fmaf(xB2, DT[IB2 * 64 + lane], recQ);
  recQ = fmaf(xB3, DT[IB3 * 64 + lane], recQ);
  recQ = fmaf(xB4, DT[IB4 * 64 + lane], recQ);
  dP_out = recP - svP;
  dQ_out = recQ - svQ;
}

#define DECLV4(p) f32x4 p##0 = {0,0,0,0}, p##1 = {0,0,0,0}, p##2 = {0,0,0,0}, p##3 = {0,0,0,0}
#define FMA16V(p, cv)                                          \
  { f32x4 s4 = splat4(cv);                                     \
    p##0 = __builtin_elementwise_fma(da, s4, p##0);            \
    p##1 = __builtin_elementwise_fma(db, s4, p##1);            \
    p##2 = __builtin_elementwise_fma(dc, s4, p##2);            \
    p##3 = __builtin_elementwise_fma(dd, s4, p##3); }

// one wave per block; 12 KB LDS for the two active signals' Q cols 0-2
__global__ __launch_bounds__(64) void k_omp(
    const float* __restrict__ D, const float* __restrict__ G,
    const float* __restrict__ DT, const float* __restrict__ ST,
    float* __restrict__ out0, float* __restrict__ lossp,
    float* __restrict__ coeffs) {
  __shared__ float QL[2][3][512];
  const int lane = threadIdx.x;
  const int hl = lane & 31;
  const bool loHalf = lane < 32;
  const int wid  = blockIdx.x;                              // 0..8191
  const int cc = wid >> 7;          // 0..63  (= n & 63)
  const int w3 = wid & 127;
  const int nbase = cc + 512 * w3;
  float* QW = &QL[0][0][0];
  float lossacc = 0.f;

  const int n0 = nbase;             const int n1 = nbase + 64;
  const int n2 = nbase + 128;       const int n3 = nbase + 192;
  const int n4 = nbase + 256;       const int n5 = nbase + 320;
  const int n6 = nbase + 384;       const int n7 = nbase + 448;
  float svA = ST[n0 * 64 + lane];
  float svB = ST[n1 * 64 + lane];
  float svC = ST[n2 * 64 + lane];
  float svD = ST[n3 * 64 + lane];
  float svE = ST[n4 * 64 + lane];
  float svF = ST[n5 * 64 + lane];
  float svG = ST[n6 * 64 + lane];
  float svH = ST[n7 * 64 + lane];

  // init_corr in SPLIT layout: lane holds atoms (lane&31)*16 + [0..15] of
  // its half's signal. 4 pairs accumulated in one D stream.
  DECLV4(pAB); DECLV4(pCD); DECLV4(pEF); DECLV4(pGH);
  const float* Dq = D + hl * 16;

  #pragma unroll 2
  for (int r = 0; r < 64; ++r) {
    const f32x4 da = *reinterpret_cast<const f32x4*>(Dq + r * KAT);
    const f32x4 db = *reinterpret_cast<const f32x4*>(Dq + r * KAT + 4);
    const f32x4 dc = *reinterpret_cast<const f32x4*>(Dq + r * KAT + 8);
    const f32x4 dd = *reinterpret_cast<const f32x4*>(Dq + r * KAT + 12);
    const float v01 = loHalf ? bcastf(svA, r) : bcastf(svB, r);
    const float v23 = loHalf ? bcastf(svC, r) : bcastf(svD, r);
    const float v45 = loHalf ? bcastf(svE, r) : bcastf(svF, r);
    const float v67 = loHalf ? bcastf(svG, r) : bcastf(svH, r);
    FMA16V(pAB, v01) FMA16V(pCD, v23) FMA16V(pEF, v45) FMA16V(pGH, v67)
  }

  float dA, dB, dC, dD, dE, dF, dG, dH;
  omp_pair(pAB0, pAB1, pAB2, pAB3, QW, G, DT, coeffs, n0, n1, lane, svA, svB, dA, dB);
  lossacc = fmaf(dA, dA, fmaf(dB, dB, lossacc));
  omp_pair(pCD0, pCD1, pCD2, pCD3, QW, G, DT, coeffs, n2, n3, lane, svC, svD, dC, dD);
  lossacc = fmaf(dC, dC, fmaf(dD, dD, lossacc));
  omp_pair(pEF0, pEF1, pEF2, pEF3, QW, G, DT, coeffs, n4, n5, lane, svE, svF, dE, dF);
  lossacc = fmaf(dE, dE, fmaf(dF, dF, lossacc));
  omp_pair(pGH0, pGH1, pGH2, pGH3, QW, G, DT, coeffs, n6, n7, lane, svG, svH, dG, dH);
  lossacc = fmaf(dG, dG, fmaf(dH, dH, lossacc));

  // out0: 8 consecutive floats per lane (32B-aligned), two dwordx4 stores
  const int obase = lane * 65536 + cc * 1024 + (w3 >> 2) * 32 + (w3 & 3) * 8;
  *reinterpret_cast<float4*>(out0 + obase) =
      make_float4(svA + dA, svB + dB, svC + dC, svD + dD);
  *reinterpret_cast<float4*>(out0 + obase + 4) =
      make_float4(svE + dE, svF + dF, svG + dG, svH + dH);

  #pragma unroll
  for (int off = 32; off > 0; off >>= 1) lossacc += __shfl_xor(lossacc, off);
  if (lane == 0) atomicAdd(lossp, lossacc * (1.25f / 4194304.f));
}

extern "C" void kernel_launch(void* const* d_in, const int* in_sizes, int n_in,
                              void* d_out, int out_size, void* d_ws, size_t ws_size,
                              hipStream_t stream) {
  const float* ze = (const float*)d_in[0];
  const float* D  = (const float*)d_in[1];
  float* out0 = (float*)d_out;
  float* lossp = out0 + 4194304;
  float* coeffs = out0 + 4194305;

  float* wsf = (float*)d_ws;
  float* G  = wsf;              // 262144 floats
  float* DT = wsf + 262144;     // 32768 floats
  float* ST = wsf + 294912;     // 4194304 floats

  // zero loss + coeffs (out0 is fully overwritten)
  (void)hipMemsetAsync((char*)d_out + 16777216ull, 0, 134217732ull, stream);

  hipLaunchKernelGGL(k_gram, dim3(1024), dim3(256), 0, stream, D, G, DT);
  hipLaunchKernelGGL(k_tr,   dim3(2048), dim3(256), 0, stream, ze, ST);
  hipLaunchKernelGGL(k_omp,  dim3(8192), dim3(64), 0, stream,
                     D, G, DT, ST, out0, lossp, coeffs);
}

// Round 19
// 170.706 us; speedup vs baseline: 1.4660x; 1.4660x over previous
//
#include <hip/hip_runtime.h>

#define NSIG  65536
#define KAT   512
#define CDIM  64

typedef float f32x4 __attribute__((ext_vector_type(4)));

__device__ __forceinline__ f32x4 splat4(float x) { return (f32x4){x, x, x, x}; }
__device__ __forceinline__ float bcastf(float v, int l) {
  return __int_as_float(__builtin_amdgcn_readlane(__float_as_int(v), l));
}
__device__ __forceinline__ unsigned umaxu(unsigned a, unsigned b) {
  return a > b ? a : b;
}
__device__ __forceinline__ unsigned dppmax(unsigned v, const int ctrl) {
  switch (ctrl) {
    case 0xB1:  return umaxu(v, (unsigned)__builtin_amdgcn_mov_dpp((int)v, 0xB1, 0xF, 0xF, true));
    case 0x4E:  return umaxu(v, (unsigned)__builtin_amdgcn_mov_dpp((int)v, 0x4E, 0xF, 0xF, true));
    case 0x124: return umaxu(v, (unsigned)__builtin_amdgcn_mov_dpp((int)v, 0x124, 0xF, 0xF, true));
    case 0x128: return umaxu(v, (unsigned)__builtin_amdgcn_mov_dpp((int)v, 0x128, 0xF, 0xF, true));
    case 0x142: return umaxu(v, (unsigned)__builtin_amdgcn_mov_dpp((int)v, 0x142, 0xF, 0xF, true));
    default:    return umaxu(v, (unsigned)__builtin_amdgcn_mov_dpp((int)v, 0x143, 0xF, 0xF, true));
  }
}

// Fused prep: blocks 0..1023 build G = D^T D and DT; blocks 1024..3071 do the
// signal-major staging transpose. Independent work, one launch, can overlap.
__global__ void k_pre(const float* __restrict__ D, float* __restrict__ G,
                      float* __restrict__ DT, const float* __restrict__ ze,
                      float* __restrict__ st) {
  __shared__ float tile[64][33];
  if (blockIdx.x < 1024) {
    int tid = blockIdx.x * 256 + threadIdx.x;      // 262144 total
    int i = tid >> 9, j = tid & 511;
    float acc = 0.f;
    #pragma unroll 8
    for (int c = 0; c < CDIM; ++c) acc = fmaf(D[c * KAT + i], D[c * KAT + j], acc);
    G[tid] = acc;
    if (tid < KAT * CDIM) {
      int k = tid >> 6, c = tid & 63;
      DT[tid] = D[c * KAT + k];
    }
  } else {
    int b = blockIdx.x - 1024;                     // 0..2047
    int cz = b >> 5;
    int h  = b & 31;
    int t  = threadIdx.x;
    #pragma unroll
    for (int q = 0; q < 8; ++q) {
      int idx = q * 256 + t;
      int bb = idx >> 5, w = idx & 31;
      tile[bb][w] = ze[bb * 65536 + cz * 1024 + h * 32 + w];
    }
    __syncthreads();
    #pragma unroll
    for (int q = 0; q < 8; ++q) {
      int idx = q * 256 + t;
      int w = idx >> 6, bb = idx & 63;
      st[(h * 2048 + w * 64 + cz) * 64 + bb] = tile[bb][w];
    }
  }
}

// ---- vector helpers (f32x4 pairs; compiler lowers to v_pk_fma_f32) ----
#define DECLV(p) f32x4 p##03 = {0,0,0,0}, p##47 = {0,0,0,0}
#define FMA8V(p, sc)                                                   \
  { f32x4 s4 = splat4(sc);                                             \
    p##03 = __builtin_elementwise_fma(d03, s4, p##03);                 \
    p##47 = __builtin_elementwise_fma(d47, s4, p##47); }
#define SEL8V(e, v03, v47)                                             \
  e = v03[0];                                                          \
  e = (jj == 1) ? v03[1] : e; e = (jj == 2) ? v03[2] : e;              \
  e = (jj == 3) ? v03[3] : e; e = (jj == 4) ? v47[0] : e;              \
  e = (jj == 5) ? v47[1] : e; e = (jj == 6) ? v47[2] : e;              \
  e = (jj == 7) ? v47[3] : e

// One full OMP solve for one signal; cr in 2 f32x4 refs. Q cols in registers
// for ortho (write-through); LDS keeps copies of cols 0-2 for the
// uniform-address w_u = Q_u[khat] broadcast extracts.
__device__ __forceinline__ float omp_one(
    f32x4& c03, f32x4& c47,
    float* __restrict__ QW,            // [3][512] float
    const float* __restrict__ G, const float* __restrict__ DT,
    float* __restrict__ coeffs,
    int n, int lane, float zv) {
  int omega = 0xFF;
  int I0 = 0, I1 = 0, I2 = 0, I3 = 0, I4 = 0;
  float L10 = 0, L20 = 0, L21 = 0;
  float L30 = 0, L31 = 0, L32 = 0;
  float L40 = 0, L41 = 0, L42 = 0, L43 = 0;
  float d1v = 1.f, d2v = 1.f, d3v = 1.f, d4v = 1.f;
  float y0v = 0, y1v = 0, y2v = 0, y3v = 0, y4v = 0;
  DECLV(Qa); DECLV(Qb); DECLV(Qc); DECLV(Qd);   // all 4 cols in regs

  f32x4* QW4 = reinterpret_cast<f32x4*>(QW);    // [3][2][64]

  #pragma unroll
  for (int it = 0; it < 5; ++it) {
    // ---- argmax of |cr|*omega: pure-DPP reduce, first-index tie-break ----
    unsigned ab0 = (omega & 1)        ? (__float_as_uint(c03[0]) & 0x7FFFFFFFu) : 0u;
    unsigned ab1 = ((omega >> 1) & 1) ? (__float_as_uint(c03[1]) & 0x7FFFFFFFu) : 0u;
    unsigned ab2 = ((omega >> 2) & 1) ? (__float_as_uint(c03[2]) & 0x7FFFFFFFu) : 0u;
    unsigned ab3 = ((omega >> 3) & 1) ? (__float_as_uint(c03[3]) & 0x7FFFFFFFu) : 0u;
    unsigned ab4 = ((omega >> 4) & 1) ? (__float_as_uint(c47[0]) & 0x7FFFFFFFu) : 0u;
    unsigned ab5 = ((omega >> 5) & 1) ? (__float_as_uint(c47[1]) & 0x7FFFFFFFu) : 0u;
    unsigned ab6 = ((omega >> 6) & 1) ? (__float_as_uint(c47[2]) & 0x7FFFFFFFu) : 0u;
    unsigned ab7 = ((omega >> 7) & 1) ? (__float_as_uint(c47[3]) & 0x7FFFFFFFu) : 0u;
    unsigned la = umaxu(umaxu(umaxu(ab0, ab1), umaxu(ab2, ab3)),
                        umaxu(umaxu(ab4, ab5), umaxu(ab6, ab7)));
    unsigned rmax = la;
    rmax = dppmax(rmax, 0xB1);    // quad xor1
    rmax = dppmax(rmax, 0x4E);    // quad xor2
    rmax = dppmax(rmax, 0x124);   // row_ror:4
    rmax = dppmax(rmax, 0x128);   // row_ror:8  -> per-row max
    rmax = dppmax(rmax, 0x142);   // row_bcast15
    rmax = dppmax(rmax, 0x143);   // row_bcast31 -> lane 63 has global max
    unsigned gmu = (unsigned)__builtin_amdgcn_readlane((int)rmax, 63);
    unsigned long long ball = __ballot(la == gmu);
    const int sl = __ffsll((long long)ball) - 1;   // lowest winning lane
    int jb = 7;
    jb = (ab6 == gmu) ? 6 : jb;
    jb = (ab5 == gmu) ? 5 : jb;
    jb = (ab4 == gmu) ? 4 : jb;
    jb = (ab3 == gmu) ? 3 : jb;
    jb = (ab2 == gmu) ? 2 : jb;
    jb = (ab1 == gmu) ? 1 : jb;
    jb = (ab0 == gmu) ? 0 : jb;
    const int jj = __builtin_amdgcn_readlane(jb, sl) & 7;
    const int khat = (sl << 3) | jj;
    if (lane == sl) omega &= ~(1 << jj);

    // ---- uniform-address LDS extractions of w_u = Q_u[khat] (issue early) --
    const int eoff = ((khat >> 2) & 1) * 256 + (khat >> 3) * 4 + (khat & 3);
    float w0 = 0.f, w1 = 0.f, w2 = 0.f, w3 = 0.f;
    if (it > 0) w0 = QW[eoff];
    if (it > 1) w1 = QW[512 + eoff];
    if (it > 2) w2 = QW[1024 + eoff];
    if (it > 3) { float e; SEL8V(e, Qd03, Qd47); w3 = bcastf(e, sl); }

    // new G row load (consumed after scalar chain)
    f32x4 na = {0, 0, 0, 0}, nbv = {0, 0, 0, 0};
    if (it < 4) {
      na  = *reinterpret_cast<const f32x4*>(G + khat * KAT + 8 * lane);
      nbv = *reinterpret_cast<const f32x4*>(G + khat * KAT + 8 * lane + 4);
    }

    // crv = cr[khat] (register select + broadcast, overlaps LDS latency)
    float crv;
    { float e; SEL8V(e, c03, c47); crv = bcastf(e, sl); }

    // ---- scalar chain: dn = rsqrt(1-||w||^2); y_it = crv*dn ----
    float s2 = 1.f - w0 * w0 - w1 * w1 - w2 * w2 - w3 * w3;
    float dn = __builtin_amdgcn_rsqf(s2);          // rsq(1.0)==1.0 at it==0
    float yn = crv * dn;
    if (it == 0) { I0 = khat; y0v = yn; }
    if (it == 1) { I1 = khat; y1v = yn; L10 = w0; d1v = dn; }
    if (it == 2) { I2 = khat; y2v = yn; L20 = w0; L21 = w1; d2v = dn; }
    if (it == 3) { I3 = khat; y3v = yn; L30 = w0; L31 = w1; L32 = w2; d3v = dn; }
    if (it == 4) { I4 = khat; y4v = yn; L40 = w0; L41 = w1; L42 = w2; L43 = w3; d4v = dn; }

    // ---- orthogonalize new column (packed FMA); rank-1 update ----
    if (it < 4) {
      f32x4 qn03 = na, qn47 = nbv;
      if (it > 0) {
        f32x4 w4 = splat4(-w0);
        qn03 = __builtin_elementwise_fma(w4, Qa03, qn03);
        qn47 = __builtin_elementwise_fma(w4, Qa47, qn47);
      }
      if (it > 1) {
        f32x4 w4 = splat4(-w1);
        qn03 = __builtin_elementwise_fma(w4, Qb03, qn03);
        qn47 = __builtin_elementwise_fma(w4, Qb47, qn47);
      }
      if (it > 2) {
        f32x4 w4 = splat4(-w2);
        qn03 = __builtin_elementwise_fma(w4, Qc03, qn03);
        qn47 = __builtin_elementwise_fma(w4, Qc47, qn47);
      }
      f32x4 dn4 = splat4(dn);
      qn03 = qn03 * dn4;
      qn47 = qn47 * dn4;
      if (it < 3) {   // LDS copy only for future uniform extracts
        QW4[it * 128 + lane]      = qn03;
        QW4[it * 128 + 64 + lane] = qn47;
      }
      if (it == 0) { Qa03 = qn03; Qa47 = qn47; }
      if (it == 1) { Qb03 = qn03; Qb47 = qn47; }
      if (it == 2) { Qc03 = qn03; Qc47 = qn47; }
      if (it == 3) { Qd03 = qn03; Qd47 = qn47; }
      f32x4 yn4 = splat4(-yn);
      c03 = __builtin_elementwise_fma(yn4, qn03, c03);
      c47 = __builtin_elementwise_fma(yn4, qn47, c47);
    }
  } // it

  // ---- back-substitution (once) + epilogue ----
  float x4 = y4v * d4v;
  float x3 = (y3v - L43 * x4) * d3v;
  float x2 = (y2v - L32 * x3 - L42 * x4) * d2v;
  float x1 = (y1v - L21 * x2 - L31 * x3 - L41 * x4) * d1v;
  float x0 =  y0v - L10 * x1 - L20 * x2 - L30 * x3 - L40 * x4;

  if (lane < 5) {
    int It = I0; float xt = x0;
    if (lane == 1) { It = I1; xt = x1; }
    if (lane == 2) { It = I2; xt = x2; }
    if (lane == 3) { It = I3; xt = x3; }
    if (lane == 4) { It = I4; xt = x4; }
    coeffs[(long)It * NSIG + n] = xt;
  }
  float rec = x0 * DT[I0 * 64 + lane];
  rec = fmaf(x1, DT[I1 * 64 + lane], rec);
  rec = fmaf(x2, DT[I2 * 64 + lane], rec);
  rec = fmaf(x3, DT[I3 * 64 + lane], rec);
  rec = fmaf(x4, DT[I4 * 64 + lane], rec);
  return rec - zv;                       // d = z_dl - z (per-lane component)
}

// one wave per block; 6 KB LDS for Q cols 0..2 extract copies
__global__ __launch_bounds__(64) void k_omp(
    const float* __restrict__ D, const float* __restrict__ G,
    const float* __restrict__ DT, const float* __restrict__ ST,
    float* __restrict__ out0, float* __restrict__ lossp,
    float* __restrict__ coeffs) {
  __shared__ float QL[3][512];
  const int lane = threadIdx.x;
  const int wid  = blockIdx.x;                              // 0..8191
  // strided signal mapping: n_j = cc + 512*w3 + 64*j (j=0..7): each lane's
  // 8 out0 values are consecutive floats -> coalesced stores, no write amp.
  const int cc = wid >> 7;          // 0..63  (= n & 63)
  const int w3 = wid & 127;
  const int nbase = cc + 512 * w3;
  const float* Dp = D + 8 * lane;
  float* QW = &QL[0][0];
  float lossacc = 0.f;

  // ONE group of 8 signals: D streamed from L2 exactly once per wave.
  const int n0 = nbase;             const int n1 = nbase + 64;
  const int n2 = nbase + 128;       const int n3 = nbase + 192;
  const int n4 = nbase + 256;       const int n5 = nbase + 320;
  const int n6 = nbase + 384;       const int n7 = nbase + 448;
  float svA = ST[n0 * 64 + lane];
  float svB = ST[n1 * 64 + lane];
  float svC = ST[n2 * 64 + lane];
  float svD = ST[n3 * 64 + lane];
  float svE = ST[n4 * 64 + lane];
  float svF = ST[n5 * 64 + lane];
  float svG = ST[n6 * 64 + lane];
  float svH = ST[n7 * 64 + lane];

  DECLV(cA); DECLV(cB); DECLV(cC); DECLV(cD);
  DECLV(cE); DECLV(cF); DECLV(cG); DECLV(cH);

  #pragma unroll 2
  for (int r = 0; r < 64; ++r) {
    const f32x4 d03 = *reinterpret_cast<const f32x4*>(Dp + r * KAT);
    const f32x4 d47 = *reinterpret_cast<const f32x4*>(Dp + r * KAT + 4);
    const float sA = bcastf(svA, r);
    const float sB = bcastf(svB, r);
    const float sC = bcastf(svC, r);
    const float sD = bcastf(svD, r);
    const float sE = bcastf(svE, r);
    const float sF = bcastf(svF, r);
    const float sG = bcastf(svG, r);
    const float sH = bcastf(svH, r);
    FMA8V(cA, sA) FMA8V(cB, sB) FMA8V(cC, sC) FMA8V(cD, sD)
    FMA8V(cE, sE) FMA8V(cF, sF) FMA8V(cG, sG) FMA8V(cH, sH)
  }

  float dA = omp_one(cA03, cA47, QW, G, DT, coeffs, n0, lane, svA);
  lossacc = fmaf(dA, dA, lossacc);
  float dB = omp_one(cB03, cB47, QW, G, DT, coeffs, n1, lane, svB);
  lossacc = fmaf(dB, dB, lossacc);
  float dC = omp_one(cC03, cC47, QW, G, DT, coeffs, n2, lane, svC);
  lossacc = fmaf(dC, dC, lossacc);
  float dD = omp_one(cD03, cD47, QW, G, DT, coeffs, n3, lane, svD);
  lossacc = fmaf(dD, dD, lossacc);
  float dE = omp_one(cE03, cE47, QW, G, DT, coeffs, n4, lane, svE);
  lossacc = fmaf(dE, dE, lossacc);
  float dF = omp_one(cF03, cF47, QW, G, DT, coeffs, n5, lane, svF);
  lossacc = fmaf(dF, dF, lossacc);
  float dG = omp_one(cG03, cG47, QW, G, DT, coeffs, n6, lane, svG);
  lossacc = fmaf(dG, dG, lossacc);
  float dH = omp_one(cH03, cH47, QW, G, DT, coeffs, n7, lane, svH);
  lossacc = fmaf(dH, dH, lossacc);

  // out0: 8 consecutive floats per lane (32B-aligned), two dwordx4 stores
  const int obase = lane * 65536 + cc * 1024 + (w3 >> 2) * 32 + (w3 & 3) * 8;
  *reinterpret_cast<float4*>(out0 + obase) =
      make_float4(svA + dA, svB + dB, svC + dC, svD + dD);
  *reinterpret_cast<float4*>(out0 + obase + 4) =
      make_float4(svE + dE, svF + dF, svG + dG, svH + dH);

  #pragma unroll
  for (int off = 32; off > 0; off >>= 1) lossacc += __shfl_xor(lossacc, off);
  if (lane == 0) atomicAdd(lossp, lossacc * (1.25f / 4194304.f));
}

extern "C" void kernel_launch(void* const* d_in, const int* in_sizes, int n_in,
                              void* d_out, int out_size, void* d_ws, size_t ws_size,
                              hipStream_t stream) {
  const float* ze = (const float*)d_in[0];
  const float* D  = (const float*)d_in[1];
  float* out0 = (float*)d_out;
  float* lossp = out0 + 4194304;
  float* coeffs = out0 + 4194305;

  float* wsf = (float*)d_ws;
  float* G  = wsf;              // 262144 floats
  float* DT = wsf + 262144;     // 32768 floats
  float* ST = wsf + 294912;     // 4194304 floats

  // zero loss + coeffs (out0 is fully overwritten)
  (void)hipMemsetAsync((char*)d_out + 16777216ull, 0, 134217732ull, stream);

  hipLaunchKernelGGL(k_pre, dim3(3072), dim3(256), 0, stream, D, G, DT, ze, ST);
  hipLaunchKernelGGL(k_omp, dim3(8192), dim3(64), 0, stream,
                     D, G, DT, ST, out0, lossp, coeffs);
}

// Round 20
// 167.186 us; speedup vs baseline: 1.4968x; 1.0211x over previous
//
#include <hip/hip_runtime.h>

#define NSIG  65536
#define KAT   512
#define CDIM  64

typedef float f32x4 __attribute__((ext_vector_type(4)));

__device__ __forceinline__ f32x4 splat4(float x) { return (f32x4){x, x, x, x}; }
__device__ __forceinline__ float bcastf(float v, int l) {
  return __int_as_float(__builtin_amdgcn_readlane(__float_as_int(v), l));
}
__device__ __forceinline__ unsigned umaxu(unsigned a, unsigned b) {
  return a > b ? a : b;
}
__device__ __forceinline__ unsigned dppmax(unsigned v, const int ctrl) {
  switch (ctrl) {
    case 0xB1:  return umaxu(v, (unsigned)__builtin_amdgcn_mov_dpp((int)v, 0xB1, 0xF, 0xF, true));
    case 0x4E:  return umaxu(v, (unsigned)__builtin_amdgcn_mov_dpp((int)v, 0x4E, 0xF, 0xF, true));
    case 0x124: return umaxu(v, (unsigned)__builtin_amdgcn_mov_dpp((int)v, 0x124, 0xF, 0xF, true));
    case 0x128: return umaxu(v, (unsigned)__builtin_amdgcn_mov_dpp((int)v, 0x128, 0xF, 0xF, true));
    case 0x142: return umaxu(v, (unsigned)__builtin_amdgcn_mov_dpp((int)v, 0x142, 0xF, 0xF, true));
    default:    return umaxu(v, (unsigned)__builtin_amdgcn_mov_dpp((int)v, 0x143, 0xF, 0xF, true));
  }
}

// Fused prep: blocks 0..1023 build G = D^T D and DT (block 0 also zeros the
// loss scalar); blocks 1024..3071 do the signal-major staging transpose;
// blocks 3072..5119 zero the coeffs output region (replaces the 134 MB
// hipMemsetAsync — its writes overlap the gram/transpose work).
__global__ void k_pre(const float* __restrict__ D, float* __restrict__ G,
                      float* __restrict__ DT, const float* __restrict__ ze,
                      float* __restrict__ st, float* __restrict__ lossp,
                      float* __restrict__ coeffs) {
  __shared__ float tile[64][33];
  if (blockIdx.x < 1024) {
    int tid = blockIdx.x * 256 + threadIdx.x;      // 262144 total
    if (tid == 0) *lossp = 0.f;
    int i = tid >> 9, j = tid & 511;
    float acc = 0.f;
    #pragma unroll 8
    for (int c = 0; c < CDIM; ++c) acc = fmaf(D[c * KAT + i], D[c * KAT + j], acc);
    G[tid] = acc;
    if (tid < KAT * CDIM) {
      int k = tid >> 6, c = tid & 63;
      DT[tid] = D[c * KAT + k];
    }
  } else if (blockIdx.x < 3072) {
    int b = blockIdx.x - 1024;                     // 0..2047
    int cz = b >> 5;
    int h  = b & 31;
    int t  = threadIdx.x;
    #pragma unroll
    for (int q = 0; q < 8; ++q) {
      int idx = q * 256 + t;
      int bb = idx >> 5, w = idx & 31;
      tile[bb][w] = ze[bb * 65536 + cz * 1024 + h * 32 + w];
    }
    __syncthreads();
    #pragma unroll
    for (int q = 0; q < 8; ++q) {
      int idx = q * 256 + t;
      int w = idx >> 6, bb = idx & 63;
      st[(h * 2048 + w * 64 + cz) * 64 + bb] = tile[bb][w];
    }
  } else {
    // zero coeffs: 2048 blocks x 16384 floats = 33554432 floats (128 MB)
    int b = blockIdx.x - 3072;                     // 0..2047
    float4* dst = reinterpret_cast<float4*>(coeffs + (long)b * 16384);
    const float4 z4 = make_float4(0.f, 0.f, 0.f, 0.f);
    #pragma unroll
    for (int q = 0; q < 16; ++q) dst[q * 256 + threadIdx.x] = z4;
  }
}

// ---- vector helpers (f32x4 pairs; compiler lowers to v_pk_fma_f32) ----
#define DECLV(p) f32x4 p##03 = {0,0,0,0}, p##47 = {0,0,0,0}
#define FMA8V(p, sc)                                                   \
  { f32x4 s4 = splat4(sc);                                             \
    p##03 = __builtin_elementwise_fma(d03, s4, p##03);                 \
    p##47 = __builtin_elementwise_fma(d47, s4, p##47); }
#define SEL8V(e, v03, v47)                                             \
  e = v03[0];                                                          \
  e = (jj == 1) ? v03[1] : e; e = (jj == 2) ? v03[2] : e;              \
  e = (jj == 3) ? v03[3] : e; e = (jj == 4) ? v47[0] : e;              \
  e = (jj == 5) ? v47[1] : e; e = (jj == 6) ? v47[2] : e;              \
  e = (jj == 7) ? v47[3] : e

// One full OMP solve for one signal; cr in 2 f32x4 refs. Q cols in registers
// for ortho (write-through); LDS keeps copies of cols 0-2 for the
// uniform-address w_u = Q_u[khat] broadcast extracts.
__device__ __forceinline__ float omp_one(
    f32x4& c03, f32x4& c47,
    float* __restrict__ QW,            // [3][512] float
    const float* __restrict__ G, const float* __restrict__ DT,
    float* __restrict__ coeffs,
    int n, int lane, float zv) {
  int omega = 0xFF;
  int I0 = 0, I1 = 0, I2 = 0, I3 = 0, I4 = 0;
  float L10 = 0, L20 = 0, L21 = 0;
  float L30 = 0, L31 = 0, L32 = 0;
  float L40 = 0, L41 = 0, L42 = 0, L43 = 0;
  float d1v = 1.f, d2v = 1.f, d3v = 1.f, d4v = 1.f;
  float y0v = 0, y1v = 0, y2v = 0, y3v = 0, y4v = 0;
  DECLV(Qa); DECLV(Qb); DECLV(Qc); DECLV(Qd);   // all 4 cols in regs

  f32x4* QW4 = reinterpret_cast<f32x4*>(QW);    // [3][2][64]

  #pragma unroll
  for (int it = 0; it < 5; ++it) {
    // ---- argmax of |cr|*omega: pure-DPP reduce, first-index tie-break ----
    unsigned ab0 = (omega & 1)        ? (__float_as_uint(c03[0]) & 0x7FFFFFFFu) : 0u;
    unsigned ab1 = ((omega >> 1) & 1) ? (__float_as_uint(c03[1]) & 0x7FFFFFFFu) : 0u;
    unsigned ab2 = ((omega >> 2) & 1) ? (__float_as_uint(c03[2]) & 0x7FFFFFFFu) : 0u;
    unsigned ab3 = ((omega >> 3) & 1) ? (__float_as_uint(c03[3]) & 0x7FFFFFFFu) : 0u;
    unsigned ab4 = ((omega >> 4) & 1) ? (__float_as_uint(c47[0]) & 0x7FFFFFFFu) : 0u;
    unsigned ab5 = ((omega >> 5) & 1) ? (__float_as_uint(c47[1]) & 0x7FFFFFFFu) : 0u;
    unsigned ab6 = ((omega >> 6) & 1) ? (__float_as_uint(c47[2]) & 0x7FFFFFFFu) : 0u;
    unsigned ab7 = ((omega >> 7) & 1) ? (__float_as_uint(c47[3]) & 0x7FFFFFFFu) : 0u;
    unsigned la = umaxu(umaxu(umaxu(ab0, ab1), umaxu(ab2, ab3)),
                        umaxu(umaxu(ab4, ab5), umaxu(ab6, ab7)));
    unsigned rmax = la;
    rmax = dppmax(rmax, 0xB1);    // quad xor1
    rmax = dppmax(rmax, 0x4E);    // quad xor2
    rmax = dppmax(rmax, 0x124);   // row_ror:4
    rmax = dppmax(rmax, 0x128);   // row_ror:8  -> per-row max
    rmax = dppmax(rmax, 0x142);   // row_bcast15
    rmax = dppmax(rmax, 0x143);   // row_bcast31 -> lane 63 has global max
    unsigned gmu = (unsigned)__builtin_amdgcn_readlane((int)rmax, 63);
    unsigned long long ball = __ballot(la == gmu);
    const int sl = __ffsll((long long)ball) - 1;   // lowest winning lane
    int jb = 7;
    jb = (ab6 == gmu) ? 6 : jb;
    jb = (ab5 == gmu) ? 5 : jb;
    jb = (ab4 == gmu) ? 4 : jb;
    jb = (ab3 == gmu) ? 3 : jb;
    jb = (ab2 == gmu) ? 2 : jb;
    jb = (ab1 == gmu) ? 1 : jb;
    jb = (ab0 == gmu) ? 0 : jb;
    const int jj = __builtin_amdgcn_readlane(jb, sl) & 7;
    const int khat = (sl << 3) | jj;
    if (lane == sl) omega &= ~(1 << jj);

    // ---- uniform-address LDS extractions of w_u = Q_u[khat] (issue early) --
    const int eoff = ((khat >> 2) & 1) * 256 + (khat >> 3) * 4 + (khat & 3);
    float w0 = 0.f, w1 = 0.f, w2 = 0.f, w3 = 0.f;
    if (it > 0) w0 = QW[eoff];
    if (it > 1) w1 = QW[512 + eoff];
    if (it > 2) w2 = QW[1024 + eoff];
    if (it > 3) { float e; SEL8V(e, Qd03, Qd47); w3 = bcastf(e, sl); }

    // new G row load (consumed after scalar chain)
    f32x4 na = {0, 0, 0, 0}, nbv = {0, 0, 0, 0};
    if (it < 4) {
      na  = *reinterpret_cast<const f32x4*>(G + khat * KAT + 8 * lane);
      nbv = *reinterpret_cast<const f32x4*>(G + khat * KAT + 8 * lane + 4);
    }

    // crv = cr[khat] (register select + broadcast, overlaps LDS latency)
    float crv;
    { float e; SEL8V(e, c03, c47); crv = bcastf(e, sl); }

    // ---- scalar chain: dn = rsqrt(1-||w||^2); y_it = crv*dn ----
    float s2 = 1.f - w0 * w0 - w1 * w1 - w2 * w2 - w3 * w3;
    float dn = __builtin_amdgcn_rsqf(s2);          // rsq(1.0)==1.0 at it==0
    float yn = crv * dn;
    if (it == 0) { I0 = khat; y0v = yn; }
    if (it == 1) { I1 = khat; y1v = yn; L10 = w0; d1v = dn; }
    if (it == 2) { I2 = khat; y2v = yn; L20 = w0; L21 = w1; d2v = dn; }
    if (it == 3) { I3 = khat; y3v = yn; L30 = w0; L31 = w1; L32 = w2; d3v = dn; }
    if (it == 4) { I4 = khat; y4v = yn; L40 = w0; L41 = w1; L42 = w2; L43 = w3; d4v = dn; }

    // ---- orthogonalize new column (packed FMA); rank-1 update ----
    if (it < 4) {
      f32x4 qn03 = na, qn47 = nbv;
      if (it > 0) {
        f32x4 w4 = splat4(-w0);
        qn03 = __builtin_elementwise_fma(w4, Qa03, qn03);
        qn47 = __builtin_elementwise_fma(w4, Qa47, qn47);
      }
      if (it > 1) {
        f32x4 w4 = splat4(-w1);
        qn03 = __builtin_elementwise_fma(w4, Qb03, qn03);
        qn47 = __builtin_elementwise_fma(w4, Qb47, qn47);
      }
      if (it > 2) {
        f32x4 w4 = splat4(-w2);
        qn03 = __builtin_elementwise_fma(w4, Qc03, qn03);
        qn47 = __builtin_elementwise_fma(w4, Qc47, qn47);
      }
      f32x4 dn4 = splat4(dn);
      qn03 = qn03 * dn4;
      qn47 = qn47 * dn4;
      if (it < 3) {   // LDS copy only for future uniform extracts
        QW4[it * 128 + lane]      = qn03;
        QW4[it * 128 + 64 + lane] = qn47;
      }
      if (it == 0) { Qa03 = qn03; Qa47 = qn47; }
      if (it == 1) { Qb03 = qn03; Qb47 = qn47; }
      if (it == 2) { Qc03 = qn03; Qc47 = qn47; }
      if (it == 3) { Qd03 = qn03; Qd47 = qn47; }
      f32x4 yn4 = splat4(-yn);
      c03 = __builtin_elementwise_fma(yn4, qn03, c03);
      c47 = __builtin_elementwise_fma(yn4, qn47, c47);
    }
  } // it

  // ---- back-substitution (once) + epilogue ----
  float x4 = y4v * d4v;
  float x3 = (y3v - L43 * x4) * d3v;
  float x2 = (y2v - L32 * x3 - L42 * x4) * d2v;
  float x1 = (y1v - L21 * x2 - L31 * x3 - L41 * x4) * d1v;
  float x0 =  y0v - L10 * x1 - L20 * x2 - L30 * x3 - L40 * x4;

  if (lane < 5) {
    int It = I0; float xt = x0;
    if (lane == 1) { It = I1; xt = x1; }
    if (lane == 2) { It = I2; xt = x2; }
    if (lane == 3) { It = I3; xt = x3; }
    if (lane == 4) { It = I4; xt = x4; }
    coeffs[(long)It * NSIG + n] = xt;
  }
  float rec = x0 * DT[I0 * 64 + lane];
  rec = fmaf(x1, DT[I1 * 64 + lane], rec);
  rec = fmaf(x2, DT[I2 * 64 + lane], rec);
  rec = fmaf(x3, DT[I3 * 64 + lane], rec);
  rec = fmaf(x4, DT[I4 * 64 + lane], rec);
  return rec - zv;                       // d = z_dl - z (per-lane component)
}

// one wave per block; 6 KB LDS for Q cols 0..2 extract copies
__global__ __launch_bounds__(64) void k_omp(
    const float* __restrict__ D, const float* __restrict__ G,
    const float* __restrict__ DT, const float* __restrict__ ST,
    float* __restrict__ out0, float* __restrict__ lossp,
    float* __restrict__ coeffs) {
  __shared__ float QL[3][512];
  const int lane = threadIdx.x;
  const int wid  = blockIdx.x;                              // 0..8191
  // strided signal mapping: n_j = cc + 512*w3 + 64*j (j=0..7): each lane's
  // 8 out0 values are consecutive floats -> coalesced stores, no write amp.
  const int cc = wid >> 7;          // 0..63  (= n & 63)
  const int w3 = wid & 127;
  const int nbase = cc + 512 * w3;
  const float* Dp = D + 8 * lane;
  float* QW = &QL[0][0];
  float lossacc = 0.f;

  // ONE group of 8 signals: D streamed from L2 exactly once per wave.
  const int n0 = nbase;             const int n1 = nbase + 64;
  const int n2 = nbase + 128;       const int n3 = nbase + 192;
  const int n4 = nbase + 256;       const int n5 = nbase + 320;
  const int n6 = nbase + 384;       const int n7 = nbase + 448;
  float svA = ST[n0 * 64 + lane];
  float svB = ST[n1 * 64 + lane];
  float svC = ST[n2 * 64 + lane];
  float svD = ST[n3 * 64 + lane];
  float svE = ST[n4 * 64 + lane];
  float svF = ST[n5 * 64 + lane];
  float svG = ST[n6 * 64 + lane];
  float svH = ST[n7 * 64 + lane];

  DECLV(cA); DECLV(cB); DECLV(cC); DECLV(cD);
  DECLV(cE); DECLV(cF); DECLV(cG); DECLV(cH);

  #pragma unroll 2
  for (int r = 0; r < 64; ++r) {
    const f32x4 d03 = *reinterpret_cast<const f32x4*>(Dp + r * KAT);
    const f32x4 d47 = *reinterpret_cast<const f32x4*>(Dp + r * KAT + 4);
    const float sA = bcastf(svA, r);
    const float sB = bcastf(svB, r);
    const float sC = bcastf(svC, r);
    const float sD = bcastf(svD, r);
    const float sE = bcastf(svE, r);
    const float sF = bcastf(svF, r);
    const float sG = bcastf(svG, r);
    const float sH = bcastf(svH, r);
    FMA8V(cA, sA) FMA8V(cB, sB) FMA8V(cC, sC) FMA8V(cD, sD)
    FMA8V(cE, sE) FMA8V(cF, sF) FMA8V(cG, sG) FMA8V(cH, sH)
  }

  float dA = omp_one(cA03, cA47, QW, G, DT, coeffs, n0, lane, svA);
  lossacc = fmaf(dA, dA, lossacc);
  float dB = omp_one(cB03, cB47, QW, G, DT, coeffs, n1, lane, svB);
  lossacc = fmaf(dB, dB, lossacc);
  float dC = omp_one(cC03, cC47, QW, G, DT, coeffs, n2, lane, svC);
  lossacc = fmaf(dC, dC, lossacc);
  float dD = omp_one(cD03, cD47, QW, G, DT, coeffs, n3, lane, svD);
  lossacc = fmaf(dD, dD, lossacc);
  float dE = omp_one(cE03, cE47, QW, G, DT, coeffs, n4, lane, svE);
  lossacc = fmaf(dE, dE, lossacc);
  float dF = omp_one(cF03, cF47, QW, G, DT, coeffs, n5, lane, svF);
  lossacc = fmaf(dF, dF, lossacc);
  float dG = omp_one(cG03, cG47, QW, G, DT, coeffs, n6, lane, svG);
  lossacc = fmaf(dG, dG, lossacc);
  float dH = omp_one(cH03, cH47, QW, G, DT, coeffs, n7, lane, svH);
  lossacc = fmaf(dH, dH, lossacc);

  // out0: 8 consecutive floats per lane (32B-aligned), two dwordx4 stores
  const int obase = lane * 65536 + cc * 1024 + (w3 >> 2) * 32 + (w3 & 3) * 8;
  *reinterpret_cast<float4*>(out0 + obase) =
      make_float4(svA + dA, svB + dB, svC + dC, svD + dD);
  *reinterpret_cast<float4*>(out0 + obase + 4) =
      make_float4(svE + dE, svF + dF, svG + dG, svH + dH);

  #pragma unroll
  for (int off = 32; off > 0; off >>= 1) lossacc += __shfl_xor(lossacc, off);
  if (lane == 0) atomicAdd(lossp, lossacc * (1.25f / 4194304.f));
}

extern "C" void kernel_launch(void* const* d_in, const int* in_sizes, int n_in,
                              void* d_out, int out_size, void* d_ws, size_t ws_size,
                              hipStream_t stream) {
  const float* ze = (const float*)d_in[0];
  const float* D  = (const float*)d_in[1];
  float* out0 = (float*)d_out;
  float* lossp = out0 + 4194304;
  float* coeffs = out0 + 4194305;

  float* wsf = (float*)d_ws;
  float* G  = wsf;              // 262144 floats
  float* DT = wsf + 262144;     // 32768 floats
  float* ST = wsf + 294912;     // 4194304 floats

  hipLaunchKernelGGL(k_pre, dim3(5120), dim3(256), 0, stream,
                     D, G, DT, ze, ST, lossp, coeffs);
  hipLaunchKernelGGL(k_omp, dim3(8192), dim3(64), 0, stream,
                     D, G, DT, ST, out0, lossp, coeffs);
}